// Round 8
// baseline (256.252 us; speedup 1.0000x reference)
//
#include <hip/hip_runtime.h>

// Problem constants (fixed by the harness/reference)
#define NUM_B 4
#define QLEN 256
#define SEQ 2048
#define NH 32
#define NKVH 8
#define HD 128
#define PAGE 16
#define NPAGES 640
#define PPS 128              // pages (blocks) per sequence
#define KD (NKVH*HD)         // 1024 floats per cache slot
#define VOFF ((size_t)NPAGES*PAGE*KD)
#define KVB 64               // kv-tile length
#define NTILES (SEQ/KVB)     // 32
#define TILE_BYTES (KVB*HD*2)// 16 KB bf16 tile image
#define NEWBASE (SEQ-QLEN)   // 1792: tokens >= this come from k/v inputs
#define QSCALE 0.08838834764831845f   // 1/sqrt(128)

typedef __attribute__((ext_vector_type(8))) short bhalf8;
typedef __attribute__((ext_vector_type(4))) float floatx4;

__device__ __forceinline__ unsigned short f2bf(float f){
  union { float f; unsigned u; } x; x.f = f;
  unsigned r = x.u + 0x7fffu + ((x.u >> 16) & 1u);   // RNE
  return (unsigned short)(r >> 16);
}

__device__ __forceinline__ bhalf8 pack8(const float* v){
  bhalf8 o;
  o[0]=(short)f2bf(v[0]); o[1]=(short)f2bf(v[1]);
  o[2]=(short)f2bf(v[2]); o[3]=(short)f2bf(v[3]);
  o[4]=(short)f2bf(v[4]); o[5]=(short)f2bf(v[5]);
  o[6]=(short)f2bf(v[6]); o[7]=(short)f2bf(v[7]);
  return o;
}

__device__ __forceinline__ void dma16(const void* g, void* l){
  __builtin_amdgcn_global_load_lds(
      (const __attribute__((address_space(1))) unsigned int*)g,
      (__attribute__((address_space(3))) unsigned int*)l, 16, 0, 0);
}

// ============================================================================
// PRIMARY PATH: one-shot bf16 repack into d_ws (swizzle pre-baked, scatter
// folded in), then DMA-staged flash attention.
// ============================================================================

// Repack: grid 4*8*32 = 1024 blocks (one per (b,kvh,kv-tile)), 256 threads.
// KT tile image: byte o = (s*256 + d*2) ^ ((s&7)<<4)   [K, row-major, swizzled]
// VT tile image: byte o = (d*128 + s*2) ^ ((d&7)<<4)   [V^T, swizzled]
__global__ __launch_bounds__(256)
void repack(const float* __restrict__ kin, const float* __restrict__ vin,
            const float* __restrict__ cache, const int* __restrict__ btab,
            unsigned short* __restrict__ KT, unsigned short* __restrict__ VT){
  __shared__ float Sf[64*132];               // padded: bank = (s*4+d)%32 spreads
  const int tid = threadIdx.x;
  const int bid = blockIdx.x;
  const int b = bid>>8, kvh = (bid>>5)&7, t = bid&31;
  const size_t tb = ((size_t)(b*NKVH + kvh)*NTILES + t)*TILE_BYTES;

  // ---- K pass: gather 64 rows f32 -> LDS -> swizzled bf16 granules ----
  #pragma unroll
  for (int i=0;i<8;i++){
    int idx = tid + i*256;                   // float4 index 0..2047
    int row = idx>>5, c4 = idx&31;
    int s_abs = t*64 + row;
    const float* src;
    if (s_abs >= NEWBASE){
      int tok = b*QLEN + (s_abs - NEWBASE);
      src = kin + (size_t)tok*KD + kvh*HD;
    } else {
      int slot = btab[b*PPS + (s_abs>>4)]*PAGE + (s_abs&15);
      src = cache + (size_t)slot*KD + kvh*HD;
    }
    *(float4*)(Sf + row*132 + c4*4) = *(const float4*)(src + c4*4);
  }
  __syncthreads();
  #pragma unroll
  for (int j=0;j<4;j++){
    int o = (tid + j*256)*16;                // granule byte offset
    int sr = o>>8;
    int d0 = ((o & 255) ^ ((sr&7)<<4))>>1;   // inverse swizzle (bits 4-6 only)
    const float* p = Sf + sr*132 + d0;
    float tmp[8] = {p[0],p[1],p[2],p[3],p[4],p[5],p[6],p[7]};
    *(bhalf8*)((char*)KT + tb + o) = pack8(tmp);
  }
  __syncthreads();

  // ---- V pass: gather -> LDS -> transposed swizzled bf16 granules ----
  #pragma unroll
  for (int i=0;i<8;i++){
    int idx = tid + i*256;
    int row = idx>>5, c4 = idx&31;
    int s_abs = t*64 + row;
    const float* src;
    if (s_abs >= NEWBASE){
      int tok = b*QLEN + (s_abs - NEWBASE);
      src = vin + (size_t)tok*KD + kvh*HD;
    } else {
      int slot = btab[b*PPS + (s_abs>>4)]*PAGE + (s_abs&15);
      src = cache + VOFF + (size_t)slot*KD + kvh*HD;
    }
    *(float4*)(Sf + row*132 + c4*4) = *(const float4*)(src + c4*4);
  }
  __syncthreads();
  #pragma unroll
  for (int j=0;j<4;j++){
    int o = (tid + j*256)*16;
    int d = o>>7;
    int s0 = ((o & 127) ^ ((d&7)<<4))>>1;
    float tmp[8];
    #pragma unroll
    for (int i2=0;i2<8;i2++) tmp[i2] = Sf[(s0+i2)*132 + d];
    *(bhalf8*)((char*)VT + tb + o) = pack8(tmp);
  }
}

// Flash attention, DMA-staged double-buffer, one barrier per tile.
// Grid: 4(b)*8(kvh)*8(rt) = 256 blocks, 512 thr; block = 128 q-rows of (b,head).
__global__ __launch_bounds__(512)
void attn_bf16(const float* __restrict__ qin,
               const unsigned short* __restrict__ KT,
               const unsigned short* __restrict__ VT,
               float* __restrict__ out){
  __shared__ unsigned short Ks[2*KVB*HD];    // 32 KB (2 bufs, swizzled image)
  __shared__ unsigned short Vt[2*HD*KVB];    // 32 KB
  __shared__ unsigned short Ps[8*16*KVB];    // 16 KB (per-wave P round-trip)

  const int tid = threadIdx.x;
  const int w = tid>>6, l = tid&63, l16 = l&15, lg = l>>4;
  const int bid = blockIdx.x;
  const int b = bid>>6, kvh = (bid>>3)&7, rt = bid&7;
  const int qlo = (rt&1)<<7;
  const int h = kvh*4 + (rt>>1);
  const size_t pan = (size_t)(b*NKVH + kvh)*NTILES;   // panel tile base

  // Q A-fragments (row = l&15, k = kc*32 + (l>>4)*8 + i), pre-scaled.
  bhalf8 aq[4];
  {
    int qi = qlo + w*16 + l16;
    const float* qp = qin + (size_t)(b*QLEN+qi)*(NH*HD) + h*HD;
    #pragma unroll
    for (int kc=0;kc<4;kc++){
      float4 f0 = *(const float4*)(qp + kc*32 + lg*8);
      float4 f1 = *(const float4*)(qp + kc*32 + lg*8 + 4);
      float tmp[8] = {f0.x*QSCALE,f0.y*QSCALE,f0.z*QSCALE,f0.w*QSCALE,
                      f1.x*QSCALE,f1.y*QSCALE,f1.z*QSCALE,f1.w*QSCALE};
      aq[kc] = pack8(tmp);
    }
  }

  // DMA one 16 KB K tile + 16 KB V tile: wave w copies its 2 KB segment,
  // 2 issues per tile per wave per tensor (lane's 16B -> lds base + lane*16).
  auto DMA = [&](int tk, int buf){
    const char* gk = (const char*)KT + (pan+tk)*TILE_BYTES + w*2048 + (size_t)l*16;
    const char* gv = (const char*)VT + (pan+tk)*TILE_BYTES + w*2048 + (size_t)l*16;
    char* lk = (char*)Ks + buf*TILE_BYTES + w*2048;
    char* lv = (char*)Vt + buf*TILE_BYTES + w*2048;
    dma16(gk,        lk);
    dma16(gk + 1024, lk + 1024);
    dma16(gv,        lv);
    dma16(gv + 1024, lv + 1024);
  };

  float mrun[4], lrun[4]; floatx4 acc[8];
  #pragma unroll
  for (int r=0;r<4;r++){ mrun[r]=-1e30f; lrun[r]=0.f; }
  #pragma unroll
  for (int dt=0;dt<8;dt++) acc[dt] = floatx4{0.f,0.f,0.f,0.f};

  const int nt = (qlo==0)?30:32;
  const int qpbase = SEQ - QLEN + qlo + w*16 + lg*4;
  unsigned short* Pw = Ps + w*(16*KVB);

  DMA(0, 0);
  __syncthreads();                           // drains vmcnt(0): tile 0 resident
  int cur = 0;

  for (int t=0;t<nt;t++){
    const int s0 = t*KVB;
    const bool pre = (t+1 < nt);
    if (pre) DMA(t+1, cur^1);                // flies under this tile's compute
    const unsigned short* K_ = Ks + cur*(KVB*HD);
    const unsigned short* V_ = Vt + cur*(HD*KVB);

    // --- QK^T ---
    floatx4 S[4];
    #pragma unroll
    for (int st=0;st<4;st++){
      S[st] = floatx4{0.f,0.f,0.f,0.f};
      int srow = st*16 + l16;
      #pragma unroll
      for (int kc=0;kc<4;kc++){
        int off = srow*256 + (kc*32+lg*8)*2; off ^= (srow&7)<<4;
        bhalf8 bk = *(bhalf8*)((char*)K_ + off);
        S[st] = __builtin_amdgcn_mfma_f32_16x16x32_bf16(aq[kc], bk, S[st], 0,0,0);
      }
    }

    // --- online softmax (row = lg*4 + r) ---
    float pe[4][4];
    float alpha[4];
    const bool masked = (t >= nt-2);
    #pragma unroll
    for (int r=0;r<4;r++){
      float v0=S[0][r], v1=S[1][r], v2=S[2][r], v3=S[3][r];
      if (masked){
        int qp_ = qpbase + r;
        if (s0 +  0 + l16 > qp_) v0 = -1e30f;
        if (s0 + 16 + l16 > qp_) v1 = -1e30f;
        if (s0 + 32 + l16 > qp_) v2 = -1e30f;
        if (s0 + 48 + l16 > qp_) v3 = -1e30f;
      }
      float tm = fmaxf(fmaxf(v0,v1),fmaxf(v2,v3));
      #pragma unroll
      for (int dd=1; dd<16; dd<<=1) tm = fmaxf(tm, __shfl_xor(tm, dd));
      float mnew = fmaxf(mrun[r], tm);
      float al = __expf(mrun[r]-mnew);
      float e0=__expf(v0-mnew), e1=__expf(v1-mnew), e2=__expf(v2-mnew), e3=__expf(v3-mnew);
      pe[0][r]=e0; pe[1][r]=e1; pe[2][r]=e2; pe[3][r]=e3;
      float sm = e0+e1+e2+e3;
      #pragma unroll
      for (int dd=1; dd<16; dd<<=1) sm += __shfl_xor(sm, dd);
      lrun[r] = lrun[r]*al + sm;
      mrun[r] = mnew;
      alpha[r] = al;
    }
    bool needr = (alpha[0]<1.f)|(alpha[1]<1.f)|(alpha[2]<1.f)|(alpha[3]<1.f);
    if (__any(needr)){
      #pragma unroll
      for (int dt=0;dt<8;dt++)
        #pragma unroll
        for (int r=0;r<4;r++) acc[dt][r] *= alpha[r];
    }

    // --- P: C-layout -> LDS bf16 -> A-layout (per-wave, lgkm-ordered) ---
    #pragma unroll
    for (int st=0;st<4;st++)
      #pragma unroll
      for (int r=0;r<4;r++){
        int row = lg*4 + r;
        int off = row*(KVB*2) + (st*16+l16)*2; off ^= (row&7)<<4;
        *(unsigned short*)((char*)Pw + off) = f2bf(pe[st][r]);
      }
    bhalf8 pa[2];
    #pragma unroll
    for (int kk=0;kk<2;kk++){
      int off = l16*(KVB*2) + (kk*32+lg*8)*2; off ^= (l16&7)<<4;
      pa[kk] = *(bhalf8*)((char*)Pw + off);
    }
    // --- PV ---
    #pragma unroll
    for (int dt=0;dt<8;dt++){
      #pragma unroll
      for (int kk=0;kk<2;kk++){
        int dr = dt*16 + l16;
        int off = dr*(KVB*2) + (kk*32+lg*8)*2; off ^= (dr&7)<<4;
        bhalf8 bv = *(bhalf8*)((char*)V_ + off);
        acc[dt] = __builtin_amdgcn_mfma_f32_16x16x32_bf16(pa[kk], bv, acc[dt], 0,0,0);
      }
    }

    __syncthreads();                         // drains this iter's DMA + barrier
    cur ^= 1;
  }

  #pragma unroll
  for (int dt=0;dt<8;dt++){
    #pragma unroll
    for (int r=0;r<4;r++){
      int qi = qlo + w*16 + lg*4 + r;
      out[(size_t)(b*QLEN+qi)*(NH*HD) + h*HD + dt*16 + l16] = acc[dt][r] / lrun[r];
    }
  }
}

// ============================================================================
// FALLBACK PATH (ws too small): round-3 kernels, proven 139 us.
// ============================================================================

__global__ void scatter_kv(const float* __restrict__ k, const float* __restrict__ v,
                           float* __restrict__ cache, const int* __restrict__ slots){
  int t = blockIdx.x, tid = threadIdx.x;
  int slot = slots[t];
  float4 kq = *(const float4*)(k + (size_t)t*KD + tid*4);
  float4 vq = *(const float4*)(v + (size_t)t*KD + tid*4);
  *(float4*)(cache + (size_t)slot*KD + tid*4) = kq;
  *(float4*)(cache + VOFF + (size_t)slot*KD + tid*4) = vq;
}

__global__ __launch_bounds__(512)
void paged_attn(const float* __restrict__ qin, const float* __restrict__ cache,
                const int* __restrict__ btab, float* __restrict__ out){
  __shared__ unsigned short Ks[2*KVB*HD];
  __shared__ unsigned short Vt[2*HD*KVB];
  __shared__ unsigned short Ps[8*16*KVB];
  __shared__ int slotT[PPS];

  const int tid = threadIdx.x;
  const int w = tid>>6, l = tid&63, l16 = l&15, lg = l>>4;
  const int bid = blockIdx.x;
  const int b = bid>>6, kvh = (bid>>3)&7, rt = bid&7;
  const int qlo = (rt&1)<<7;
  const int h = kvh*4 + (rt>>1);

  if (tid < PPS) slotT[tid] = btab[b*PPS + tid]*PAGE;

  bhalf8 aq[4];
  {
    int qi = qlo + w*16 + l16;
    const float* qp = qin + (size_t)(b*QLEN+qi)*(NH*HD) + h*HD;
    #pragma unroll
    for (int kc=0;kc<4;kc++){
      float4 f0 = *(const float4*)(qp + kc*32 + lg*8);
      float4 f1 = *(const float4*)(qp + kc*32 + lg*8 + 4);
      float tmp[8] = {f0.x*QSCALE,f0.y*QSCALE,f0.z*QSCALE,f0.w*QSCALE,
                      f1.x*QSCALE,f1.y*QSCALE,f1.z*QSCALE,f1.w*QSCALE};
      aq[kc] = pack8(tmp);
    }
  }
  __syncthreads();

  float4 ka0,ka1,kb0,kb1;
  float va[8], vb[8];
  const int dchK = tid&15, sA = tid>>4;
  const int dV = tid&127, scV = tid>>7;

  auto LOAD = [&](int t){
    const int s0 = t*KVB;
    int pA = s0 + sA, pB = pA + 32;
    int slA = slotT[pA>>4] + (pA&15);
    int slB = slotT[pB>>4] + (pB&15);
    const float4* kpA = (const float4*)(cache + (size_t)slA*KD + kvh*HD + dchK*8);
    const float4* kpB = (const float4*)(cache + (size_t)slB*KD + kvh*HD + dchK*8);
    ka0 = kpA[0]; ka1 = kpA[1]; kb0 = kpB[0]; kb1 = kpB[1];
    int sb0 = scV*8, sb1 = sb0 + 32;
    const float* vp0 = cache + VOFF + (size_t)(slotT[(s0+sb0)>>4] + (sb0&15))*KD + kvh*HD + dV;
    const float* vp1 = cache + VOFF + (size_t)(slotT[(s0+sb1)>>4] + (sb1&15))*KD + kvh*HD + dV;
    #pragma unroll
    for (int i=0;i<8;i++){ va[i] = vp0[(size_t)i*KD]; vb[i] = vp1[(size_t)i*KD]; }
  };

  auto WRITE = [&](int buf){
    unsigned short* K_ = Ks + buf*(KVB*HD);
    unsigned short* V_ = Vt + buf*(HD*KVB);
    {
      float t0[8]={ka0.x,ka0.y,ka0.z,ka0.w,ka1.x,ka1.y,ka1.z,ka1.w};
      int off0 = sA*256 + dchK*16; off0 ^= (sA&7)<<4;
      *(bhalf8*)((char*)K_ + off0) = pack8(t0);
      float t1[8]={kb0.x,kb0.y,kb0.z,kb0.w,kb1.x,kb1.y,kb1.z,kb1.w};
      int sB = sA + 32;
      int off1 = sB*256 + dchK*16; off1 ^= (sB&7)<<4;
      *(bhalf8*)((char*)K_ + off1) = pack8(t1);
    }
    {
      int sb0 = scV*8, sb1 = sb0 + 32;
      int off0 = dV*(KVB*2) + sb0*2; off0 ^= (dV&7)<<4;
      *(bhalf8*)((char*)V_ + off0) = pack8(va);
      int off1 = dV*(KVB*2) + sb1*2; off1 ^= (dV&7)<<4;
      *(bhalf8*)((char*)V_ + off1) = pack8(vb);
    }
  };

  float mrun[4], lrun[4]; floatx4 acc[8];
  #pragma unroll
  for (int r=0;r<4;r++){ mrun[r]=-1e30f; lrun[r]=0.f; }
  #pragma unroll
  for (int dt=0;dt<8;dt++) acc[dt] = floatx4{0.f,0.f,0.f,0.f};

  const int nt = (qlo==0)?30:32;
  const int qpbase = SEQ - QLEN + qlo + w*16 + lg*4;
  unsigned short* Pw = Ps + w*(16*KVB);

  LOAD(0); WRITE(0);
  __syncthreads();
  int cur = 0;

  for (int t=0;t<nt;t++){
    const int s0 = t*KVB;
    const bool pre = (t+1 < nt);
    if (pre) LOAD(t+1);
    const unsigned short* K_ = Ks + cur*(KVB*HD);
    const unsigned short* V_ = Vt + cur*(HD*KVB);

    floatx4 S[4];
    #pragma unroll
    for (int st=0;st<4;st++){
      S[st] = floatx4{0.f,0.f,0.f,0.f};
      int srow = st*16 + l16;
      #pragma unroll
      for (int kc=0;kc<4;kc++){
        int off = srow*256 + (kc*32+lg*8)*2; off ^= (srow&7)<<4;
        bhalf8 bk = *(bhalf8*)((char*)K_ + off);
        S[st] = __builtin_amdgcn_mfma_f32_16x16x32_bf16(aq[kc], bk, S[st], 0,0,0);
      }
    }

    float pe[4][4];
    float alpha[4];
    const bool masked = (t >= nt-2);
    #pragma unroll
    for (int r=0;r<4;r++){
      float v0=S[0][r], v1=S[1][r], v2=S[2][r], v3=S[3][r];
      if (masked){
        int qp_ = qpbase + r;
        if (s0 +  0 + l16 > qp_) v0 = -1e30f;
        if (s0 + 16 + l16 > qp_) v1 = -1e30f;
        if (s0 + 32 + l16 > qp_) v2 = -1e30f;
        if (s0 + 48 + l16 > qp_) v3 = -1e30f;
      }
      float tm = fmaxf(fmaxf(v0,v1),fmaxf(v2,v3));
      #pragma unroll
      for (int dd=1; dd<16; dd<<=1) tm = fmaxf(tm, __shfl_xor(tm, dd));
      float mnew = fmaxf(mrun[r], tm);
      float al = __expf(mrun[r]-mnew);
      float e0=__expf(v0-mnew), e1=__expf(v1-mnew), e2=__expf(v2-mnew), e3=__expf(v3-mnew);
      pe[0][r]=e0; pe[1][r]=e1; pe[2][r]=e2; pe[3][r]=e3;
      float sm = e0+e1+e2+e3;
      #pragma unroll
      for (int dd=1; dd<16; dd<<=1) sm += __shfl_xor(sm, dd);
      lrun[r] = lrun[r]*al + sm;
      mrun[r] = mnew;
      alpha[r] = al;
    }
    bool needr = (alpha[0]<1.f)|(alpha[1]<1.f)|(alpha[2]<1.f)|(alpha[3]<1.f);
    if (__any(needr)){
      #pragma unroll
      for (int dt=0;dt<8;dt++)
        #pragma unroll
        for (int r=0;r<4;r++) acc[dt][r] *= alpha[r];
    }

    #pragma unroll
    for (int st=0;st<4;st++)
      #pragma unroll
      for (int r=0;r<4;r++){
        int row = lg*4 + r;
        int off = row*(KVB*2) + (st*16+l16)*2; off ^= (row&7)<<4;
        *(unsigned short*)((char*)Pw + off) = f2bf(pe[st][r]);
      }
    bhalf8 pa[2];
    #pragma unroll
    for (int kk=0;kk<2;kk++){
      int off = l16*(KVB*2) + (kk*32+lg*8)*2; off ^= (l16&7)<<4;
      pa[kk] = *(bhalf8*)((char*)Pw + off);
    }
    #pragma unroll
    for (int dt=0;dt<8;dt++){
      #pragma unroll
      for (int kk=0;kk<2;kk++){
        int dr = dt*16 + l16;
        int off = dr*(KVB*2) + (kk*32+lg*8)*2; off ^= (dr&7)<<4;
        bhalf8 bv = *(bhalf8*)((char*)V_ + off);
        acc[dt] = __builtin_amdgcn_mfma_f32_16x16x32_bf16(pa[kk], bv, acc[dt], 0,0,0);
      }
    }

    if (pre){
      WRITE(cur^1);
      __syncthreads();
    }
    cur ^= 1;
  }

  #pragma unroll
  for (int dt=0;dt<8;dt++){
    #pragma unroll
    for (int r=0;r<4;r++){
      int qi = qlo + w*16 + lg*4 + r;
      out[(size_t)(b*QLEN+qi)*(NH*HD) + h*HD + dt*16 + l16] = acc[dt][r] / lrun[r];
    }
  }
}

extern "C" void kernel_launch(void* const* d_in, const int* in_sizes, int n_in,
                              void* d_out, int out_size, void* d_ws, size_t ws_size,
                              hipStream_t stream) {
  const float* q = (const float*)d_in[0];
  const float* k = (const float*)d_in[1];
  const float* v = (const float*)d_in[2];
  float*       cache = (float*)d_in[3];
  const int*   slot_mapping = (const int*)d_in[4];
  const int*   block_tables = (const int*)d_in[5];
  float* out = (float*)d_out;

  const size_t need = (size_t)2 * NUM_B * NKVH * NTILES * TILE_BYTES;  // 32 MB
  if (ws_size >= need){
    unsigned short* KT = (unsigned short*)d_ws;
    unsigned short* VT = KT + (need/2)/2;    // second half of ws, in shorts
    repack<<<NUM_B*NKVH*NTILES, 256, 0, stream>>>(k, v, cache, block_tables, KT, VT);
    attn_bf16<<<NUM_B*NKVH*8, 512, 0, stream>>>(q, KT, VT, out);
  } else {
    scatter_kv<<<NUM_B*QLEN, 256, 0, stream>>>(k, v, cache, slot_mapping);
    paged_attn<<<NUM_B*NKVH*8, 512, 0, stream>>>(q, cache, block_tables, out);
  }
}

// Round 10
// 250.133 us; speedup vs baseline: 1.0245x; 1.0245x over previous
//
#include <hip/hip_runtime.h>

// Problem constants (fixed by the harness/reference)
#define NUM_B 4
#define QLEN 256
#define SEQ 2048
#define NH 32
#define NKVH 8
#define HD 128
#define PAGE 16
#define NPAGES 640
#define PPS 128              // pages (blocks) per sequence
#define KD (NKVH*HD)         // 1024 floats per cache slot
#define VOFF ((size_t)NPAGES*PAGE*KD)
#define KVB 64               // kv-tile length
#define NTILES (SEQ/KVB)     // 32
#define TILE_BYTES (KVB*HD*2)// 16 KB bf16 tile image
#define NEWBASE (SEQ-QLEN)   // 1792: tokens >= this come from k/v inputs
#define QSCALE 0.08838834764831845f   // 1/sqrt(128)

typedef __attribute__((ext_vector_type(8))) short bhalf8;
typedef __attribute__((ext_vector_type(4))) float floatx4;

__device__ __forceinline__ unsigned short f2bf(float f){
  union { float f; unsigned u; } x; x.f = f;
  unsigned r = x.u + 0x7fffu + ((x.u >> 16) & 1u);   // RNE
  return (unsigned short)(r >> 16);
}

__device__ __forceinline__ bhalf8 pack8(const float* v){
  bhalf8 o;
  o[0]=(short)f2bf(v[0]); o[1]=(short)f2bf(v[1]);
  o[2]=(short)f2bf(v[2]); o[3]=(short)f2bf(v[3]);
  o[4]=(short)f2bf(v[4]); o[5]=(short)f2bf(v[5]);
  o[6]=(short)f2bf(v[6]); o[7]=(short)f2bf(v[7]);
  return o;
}

__device__ __forceinline__ void dma16(const void* g, void* l){
  __builtin_amdgcn_global_load_lds(
      (const __attribute__((address_space(1))) unsigned int*)g,
      (__attribute__((address_space(3))) unsigned int*)l, 16, 0, 0);
}

// ============================================================================
// PRIMARY PATH: one-shot bf16 repack into d_ws (swizzle pre-baked, scatter
// folded in), then DMA-staged flash attention with 2 blocks/CU.
// ============================================================================

// Repack: grid 4*8*32 = 1024 blocks (one per (b,kvh,kv-tile)), 256 threads.
// KT tile image: byte o = (s*256 + d*2) ^ ((s&7)<<4)   [K, row-major, swizzled]
// VT tile image: byte o = (d*128 + s*2) ^ ((d&7)<<4)   [V^T, swizzled]
__global__ __launch_bounds__(256)
void repack(const float* __restrict__ kin, const float* __restrict__ vin,
            const float* __restrict__ cache, const int* __restrict__ btab,
            unsigned short* __restrict__ KT, unsigned short* __restrict__ VT){
  __shared__ float Sf[64*132];               // padded: bank = (s*4+d)%32 spreads
  const int tid = threadIdx.x;
  const int bid = blockIdx.x;
  const int b = bid>>8, kvh = (bid>>5)&7, t = bid&31;
  const size_t tb = ((size_t)(b*NKVH + kvh)*NTILES + t)*TILE_BYTES;

  // ---- K pass: gather 64 rows f32 -> LDS -> swizzled bf16 granules ----
  #pragma unroll
  for (int i=0;i<8;i++){
    int idx = tid + i*256;                   // float4 index 0..2047
    int row = idx>>5, c4 = idx&31;
    int s_abs = t*64 + row;
    const float* src;
    if (s_abs >= NEWBASE){
      int tok = b*QLEN + (s_abs - NEWBASE);
      src = kin + (size_t)tok*KD + kvh*HD;
    } else {
      int slot = btab[b*PPS + (s_abs>>4)]*PAGE + (s_abs&15);
      src = cache + (size_t)slot*KD + kvh*HD;
    }
    *(float4*)(Sf + row*132 + c4*4) = *(const float4*)(src + c4*4);
  }
  __syncthreads();
  #pragma unroll
  for (int j=0;j<4;j++){
    int o = (tid + j*256)*16;                // granule byte offset
    int sr = o>>8;
    int d0 = ((o & 255) ^ ((sr&7)<<4))>>1;   // inverse swizzle (bits 4-6 only)
    const float* p = Sf + sr*132 + d0;
    float tmp[8] = {p[0],p[1],p[2],p[3],p[4],p[5],p[6],p[7]};
    *(bhalf8*)((char*)KT + tb + o) = pack8(tmp);
  }
  __syncthreads();

  // ---- V pass: gather -> LDS -> transposed swizzled bf16 granules ----
  #pragma unroll
  for (int i=0;i<8;i++){
    int idx = tid + i*256;
    int row = idx>>5, c4 = idx&31;
    int s_abs = t*64 + row;
    const float* src;
    if (s_abs >= NEWBASE){
      int tok = b*QLEN + (s_abs - NEWBASE);
      src = vin + (size_t)tok*KD + kvh*HD;
    } else {
      int slot = btab[b*PPS + (s_abs>>4)]*PAGE + (s_abs&15);
      src = cache + VOFF + (size_t)slot*KD + kvh*HD;
    }
    *(float4*)(Sf + row*132 + c4*4) = *(const float4*)(src + c4*4);
  }
  __syncthreads();
  #pragma unroll
  for (int j=0;j<4;j++){
    int o = (tid + j*256)*16;
    int d = o>>7;
    int s0 = ((o & 127) ^ ((d&7)<<4))>>1;
    float tmp[8];
    #pragma unroll
    for (int i2=0;i2<8;i2++) tmp[i2] = Sf[(s0+i2)*132 + d];
    *(bhalf8*)((char*)VT + tb + o) = pack8(tmp);
  }
}

// Flash attention, DMA-staged double-buffer, one barrier per tile.
// Grid: 4(b)*8(kvh)*16(rt) = 512 blocks, 256 thr (4 waves); block = 64 q-rows
// of one (b, query-head). 72 KB LDS -> 2 blocks/CU: independent blocks
// overlap each other's barrier/vmcnt stalls.
__global__ __launch_bounds__(256)
void attn_bf16(const float* __restrict__ qin,
               const unsigned short* __restrict__ KT,
               const unsigned short* __restrict__ VT,
               float* __restrict__ out){
  __shared__ unsigned short Ks[2*KVB*HD];    // 32 KB (2 bufs, swizzled image)
  __shared__ unsigned short Vt[2*HD*KVB];    // 32 KB
  __shared__ unsigned short Ps[4*16*KVB];    // 8 KB (per-wave P round-trip)

  const int tid = threadIdx.x;
  const int w = tid>>6, l = tid&63, l16 = l&15, lg = l>>4;
  const int bid = blockIdx.x;
  const int b = bid>>7, kvh = (bid>>4)&7, rt = bid&15;
  const int hg = rt>>2, qq = rt&3;           // head-in-group, q-quarter
  const int qbase = qq<<6;                   // 0/64/128/192 within 256 queries
  const int h = kvh*4 + hg;                  // query head
  const size_t pan = (size_t)(b*NKVH + kvh)*NTILES;   // panel tile base

  // Q A-fragments (row = l&15, k = kc*32 + (l>>4)*8 + i), pre-scaled.
  bhalf8 aq[4];
  {
    int qi = qbase + w*16 + l16;
    const float* qp = qin + (size_t)(b*QLEN+qi)*(NH*HD) + h*HD;
    #pragma unroll
    for (int kc=0;kc<4;kc++){
      float4 f0 = *(const float4*)(qp + kc*32 + lg*8);
      float4 f1 = *(const float4*)(qp + kc*32 + lg*8 + 4);
      float tmp[8] = {f0.x*QSCALE,f0.y*QSCALE,f0.z*QSCALE,f0.w*QSCALE,
                      f1.x*QSCALE,f1.y*QSCALE,f1.z*QSCALE,f1.w*QSCALE};
      aq[kc] = pack8(tmp);
    }
  }

  // DMA one 16 KB K tile + 16 KB V tile: wave w copies its 4 KB segment,
  // 4 issues per tile per wave per tensor (lane's 16B -> lds base + lane*16).
  auto DMA = [&](int tk, int buf){
    const char* gk = (const char*)KT + (pan+tk)*TILE_BYTES + w*4096 + (size_t)l*16;
    const char* gv = (const char*)VT + (pan+tk)*TILE_BYTES + w*4096 + (size_t)l*16;
    char* lk = (char*)Ks + buf*TILE_BYTES + w*4096;
    char* lv = (char*)Vt + buf*TILE_BYTES + w*4096;
    #pragma unroll
    for (int i=0;i<4;i++){
      dma16(gk + i*1024, lk + i*1024);
      dma16(gv + i*1024, lv + i*1024);
    }
  };

  float mrun[4], lrun[4]; floatx4 acc[8];
  #pragma unroll
  for (int r=0;r<4;r++){ mrun[r]=-1e30f; lrun[r]=0.f; }
  #pragma unroll
  for (int dt=0;dt<8;dt++) acc[dt] = floatx4{0.f,0.f,0.f,0.f};

  const int nt = 29 + qq;                    // q-span 64 == kv-span: last tile only masked
  const int qpbase = NEWBASE + qbase + w*16 + lg*4;   // +r = abs pos of D-layout row r
  unsigned short* Pw = Ps + w*(16*KVB);

  DMA(0, 0);
  __syncthreads();                           // drains vmcnt(0): tile 0 resident
  int cur = 0;

  for (int t=0;t<nt;t++){
    const int s0 = t*KVB;
    const bool pre = (t+1 < nt);
    if (pre) DMA(t+1, cur^1);                // flies under this tile's compute
    const unsigned short* K_ = Ks + cur*(KVB*HD);
    const unsigned short* V_ = Vt + cur*(HD*KVB);

    // --- QK^T ---
    floatx4 S[4];
    #pragma unroll
    for (int st=0;st<4;st++){
      S[st] = floatx4{0.f,0.f,0.f,0.f};
      int srow = st*16 + l16;
      #pragma unroll
      for (int kc=0;kc<4;kc++){
        int off = srow*256 + (kc*32+lg*8)*2; off ^= (srow&7)<<4;
        bhalf8 bk = *(bhalf8*)((char*)K_ + off);
        S[st] = __builtin_amdgcn_mfma_f32_16x16x32_bf16(aq[kc], bk, S[st], 0,0,0);
      }
    }

    // --- online softmax (row = lg*4 + r) ---
    float pe[4][4];
    float alpha[4];
    const bool masked = (t == nt-1);
    #pragma unroll
    for (int r=0;r<4;r++){
      float v0=S[0][r], v1=S[1][r], v2=S[2][r], v3=S[3][r];
      if (masked){
        int qp_ = qpbase + r;
        if (s0 +  0 + l16 > qp_) v0 = -1e30f;
        if (s0 + 16 + l16 > qp_) v1 = -1e30f;
        if (s0 + 32 + l16 > qp_) v2 = -1e30f;
        if (s0 + 48 + l16 > qp_) v3 = -1e30f;
      }
      float tm = fmaxf(fmaxf(v0,v1),fmaxf(v2,v3));
      #pragma unroll
      for (int dd=1; dd<16; dd<<=1) tm = fmaxf(tm, __shfl_xor(tm, dd));
      float mnew = fmaxf(mrun[r], tm);
      float al = __expf(mrun[r]-mnew);
      float e0=__expf(v0-mnew), e1=__expf(v1-mnew), e2=__expf(v2-mnew), e3=__expf(v3-mnew);
      pe[0][r]=e0; pe[1][r]=e1; pe[2][r]=e2; pe[3][r]=e3;
      float sm = e0+e1+e2+e3;
      #pragma unroll
      for (int dd=1; dd<16; dd<<=1) sm += __shfl_xor(sm, dd);
      lrun[r] = lrun[r]*al + sm;
      mrun[r] = mnew;
      alpha[r] = al;
    }
    bool needr = (alpha[0]<1.f)|(alpha[1]<1.f)|(alpha[2]<1.f)|(alpha[3]<1.f);
    if (__any(needr)){
      #pragma unroll
      for (int dt=0;dt<8;dt++)
        #pragma unroll
        for (int r=0;r<4;r++) acc[dt][r] *= alpha[r];
    }

    // --- P: C-layout -> LDS bf16 -> A-layout (per-wave, lgkm-ordered) ---
    #pragma unroll
    for (int st=0;st<4;st++)
      #pragma unroll
      for (int r=0;r<4;r++){
        int row = lg*4 + r;
        int off = row*(KVB*2) + (st*16+l16)*2; off ^= (row&7)<<4;
        *(unsigned short*)((char*)Pw + off) = f2bf(pe[st][r]);
      }
    bhalf8 pa[2];
    #pragma unroll
    for (int kk=0;kk<2;kk++){
      int off = l16*(KVB*2) + (kk*32+lg*8)*2; off ^= (l16&7)<<4;
      pa[kk] = *(bhalf8*)((char*)Pw + off);
    }
    // --- PV ---
    #pragma unroll
    for (int dt=0;dt<8;dt++){
      #pragma unroll
      for (int kk=0;kk<2;kk++){
        int dr = dt*16 + l16;
        int off = dr*(KVB*2) + (kk*32+lg*8)*2; off ^= (dr&7)<<4;
        bhalf8 bv = *(bhalf8*)((char*)V_ + off);
        acc[dt] = __builtin_amdgcn_mfma_f32_16x16x32_bf16(pa[kk], bv, acc[dt], 0,0,0);
      }
    }

    __syncthreads();                         // drains this iter's DMA + barrier
    cur ^= 1;
  }

  #pragma unroll
  for (int dt=0;dt<8;dt++){
    #pragma unroll
    for (int r=0;r<4;r++){
      int qi = qbase + w*16 + lg*4 + r;
      out[(size_t)(b*QLEN+qi)*(NH*HD) + h*HD + dt*16 + l16] = acc[dt][r] / lrun[r];
    }
  }
}

// ============================================================================
// FALLBACK PATH (ws too small): round-3 kernels, proven 139 us.
// ============================================================================

__global__ void scatter_kv(const float* __restrict__ k, const float* __restrict__ v,
                           float* __restrict__ cache, const int* __restrict__ slots){
  int t = blockIdx.x, tid = threadIdx.x;
  int slot = slots[t];
  float4 kq = *(const float4*)(k + (size_t)t*KD + tid*4);
  float4 vq = *(const float4*)(v + (size_t)t*KD + tid*4);
  *(float4*)(cache + (size_t)slot*KD + tid*4) = kq;
  *(float4*)(cache + VOFF + (size_t)slot*KD + tid*4) = vq;
}

__global__ __launch_bounds__(512)
void paged_attn(const float* __restrict__ qin, const float* __restrict__ cache,
                const int* __restrict__ btab, float* __restrict__ out){
  __shared__ unsigned short Ks[2*KVB*HD];
  __shared__ unsigned short Vt[2*HD*KVB];
  __shared__ unsigned short Ps[8*16*KVB];
  __shared__ int slotT[PPS];

  const int tid = threadIdx.x;
  const int w = tid>>6, l = tid&63, l16 = l&15, lg = l>>4;
  const int bid = blockIdx.x;
  const int b = bid>>6, kvh = (bid>>3)&7, rt = bid&7;
  const int qlo = (rt&1)<<7;
  const int h = kvh*4 + (rt>>1);

  if (tid < PPS) slotT[tid] = btab[b*PPS + tid]*PAGE;

  bhalf8 aq[4];
  {
    int qi = qlo + w*16 + l16;
    const float* qp = qin + (size_t)(b*QLEN+qi)*(NH*HD) + h*HD;
    #pragma unroll
    for (int kc=0;kc<4;kc++){
      float4 f0 = *(const float4*)(qp + kc*32 + lg*8);
      float4 f1 = *(const float4*)(qp + kc*32 + lg*8 + 4);
      float tmp[8] = {f0.x*QSCALE,f0.y*QSCALE,f0.z*QSCALE,f0.w*QSCALE,
                      f1.x*QSCALE,f1.y*QSCALE,f1.z*QSCALE,f1.w*QSCALE};
      aq[kc] = pack8(tmp);
    }
  }
  __syncthreads();

  float4 ka0,ka1,kb0,kb1;
  float va[8], vb[8];
  const int dchK = tid&15, sA = tid>>4;
  const int dV = tid&127, scV = tid>>7;

  auto LOAD = [&](int t){
    const int s0 = t*KVB;
    int pA = s0 + sA, pB = pA + 32;
    int slA = slotT[pA>>4] + (pA&15);
    int slB = slotT[pB>>4] + (pB&15);
    const float4* kpA = (const float4*)(cache + (size_t)slA*KD + kvh*HD + dchK*8);
    const float4* kpB = (const float4*)(cache + (size_t)slB*KD + kvh*HD + dchK*8);
    ka0 = kpA[0]; ka1 = kpA[1]; kb0 = kpB[0]; kb1 = kpB[1];
    int sb0 = scV*8, sb1 = sb0 + 32;
    const float* vp0 = cache + VOFF + (size_t)(slotT[(s0+sb0)>>4] + (sb0&15))*KD + kvh*HD + dV;
    const float* vp1 = cache + VOFF + (size_t)(slotT[(s0+sb1)>>4] + (sb1&15))*KD + kvh*HD + dV;
    #pragma unroll
    for (int i=0;i<8;i++){ va[i] = vp0[(size_t)i*KD]; vb[i] = vp1[(size_t)i*KD]; }
  };

  auto WRITE = [&](int buf){
    unsigned short* K_ = Ks + buf*(KVB*HD);
    unsigned short* V_ = Vt + buf*(HD*KVB);
    {
      float t0[8]={ka0.x,ka0.y,ka0.z,ka0.w,ka1.x,ka1.y,ka1.z,ka1.w};
      int off0 = sA*256 + dchK*16; off0 ^= (sA&7)<<4;
      *(bhalf8*)((char*)K_ + off0) = pack8(t0);
      float t1[8]={kb0.x,kb0.y,kb0.z,kb0.w,kb1.x,kb1.y,kb1.z,kb1.w};
      int sB = sA + 32;
      int off1 = sB*256 + dchK*16; off1 ^= (sB&7)<<4;
      *(bhalf8*)((char*)K_ + off1) = pack8(t1);
    }
    {
      int sb0 = scV*8, sb1 = sb0 + 32;
      int off0 = dV*(KVB*2) + sb0*2; off0 ^= (dV&7)<<4;
      *(bhalf8*)((char*)V_ + off0) = pack8(va);
      int off1 = dV*(KVB*2) + sb1*2; off1 ^= (dV&7)<<4;
      *(bhalf8*)((char*)V_ + off1) = pack8(vb);
    }
  };

  float mrun[4], lrun[4]; floatx4 acc[8];
  #pragma unroll
  for (int r=0;r<4;r++){ mrun[r]=-1e30f; lrun[r]=0.f; }
  #pragma unroll
  for (int dt=0;dt<8;dt++) acc[dt] = floatx4{0.f,0.f,0.f,0.f};

  const int nt = (qlo==0)?30:32;
  const int qpbase = SEQ - QLEN + qlo + w*16 + lg*4;
  unsigned short* Pw = Ps + w*(16*KVB);

  LOAD(0); WRITE(0);
  __syncthreads();
  int cur = 0;

  for (int t=0;t<nt;t++){
    const int s0 = t*KVB;
    const bool pre = (t+1 < nt);
    if (pre) LOAD(t+1);
    const unsigned short* K_ = Ks + cur*(KVB*HD);
    const unsigned short* V_ = Vt + cur*(HD*KVB);

    floatx4 S[4];
    #pragma unroll
    for (int st=0;st<4;st++){
      S[st] = floatx4{0.f,0.f,0.f,0.f};
      int srow = st*16 + l16;
      #pragma unroll
      for (int kc=0;kc<4;kc++){
        int off = srow*256 + (kc*32+lg*8)*2; off ^= (srow&7)<<4;
        bhalf8 bk = *(bhalf8*)((char*)K_ + off);
        S[st] = __builtin_amdgcn_mfma_f32_16x16x32_bf16(aq[kc], bk, S[st], 0,0,0);
      }
    }

    float pe[4][4];
    float alpha[4];
    const bool masked = (t >= nt-2);
    #pragma unroll
    for (int r=0;r<4;r++){
      float v0=S[0][r], v1=S[1][r], v2=S[2][r], v3=S[3][r];
      if (masked){
        int qp_ = qpbase + r;
        if (s0 +  0 + l16 > qp_) v0 = -1e30f;
        if (s0 + 16 + l16 > qp_) v1 = -1e30f;
        if (s0 + 32 + l16 > qp_) v2 = -1e30f;
        if (s0 + 48 + l16 > qp_) v3 = -1e30f;
      }
      float tm = fmaxf(fmaxf(v0,v1),fmaxf(v2,v3));
      #pragma unroll
      for (int dd=1; dd<16; dd<<=1) tm = fmaxf(tm, __shfl_xor(tm, dd));
      float mnew = fmaxf(mrun[r], tm);
      float al = __expf(mrun[r]-mnew);
      float e0=__expf(v0-mnew), e1=__expf(v1-mnew), e2=__expf(v2-mnew), e3=__expf(v3-mnew);
      pe[0][r]=e0; pe[1][r]=e1; pe[2][r]=e2; pe[3][r]=e3;
      float sm = e0+e1+e2+e3;
      #pragma unroll
      for (int dd=1; dd<16; dd<<=1) sm += __shfl_xor(sm, dd);
      lrun[r] = lrun[r]*al + sm;
      mrun[r] = mnew;
      alpha[r] = al;
    }
    bool needr = (alpha[0]<1.f)|(alpha[1]<1.f)|(alpha[2]<1.f)|(alpha[3]<1.f);
    if (__any(needr)){
      #pragma unroll
      for (int dt=0;dt<8;dt++)
        #pragma unroll
        for (int r=0;r<4;r++) acc[dt][r] *= alpha[r];
    }

    #pragma unroll
    for (int st=0;st<4;st++)
      #pragma unroll
      for (int r=0;r<4;r++){
        int row = lg*4 + r;
        int off = row*(KVB*2) + (st*16+l16)*2; off ^= (row&7)<<4;
        *(unsigned short*)((char*)Pw + off) = f2bf(pe[st][r]);
      }
    bhalf8 pa[2];
    #pragma unroll
    for (int kk=0;kk<2;kk++){
      int off = l16*(KVB*2) + (kk*32+lg*8)*2; off ^= (l16&7)<<4;
      pa[kk] = *(bhalf8*)((char*)Pw + off);
    }
    #pragma unroll
    for (int dt=0;dt<8;dt++){
      #pragma unroll
      for (int kk=0;kk<2;kk++){
        int dr = dt*16 + l16;
        int off = dr*(KVB*2) + (kk*32+lg*8)*2; off ^= (dr&7)<<4;
        bhalf8 bv = *(bhalf8*)((char*)V_ + off);
        acc[dt] = __builtin_amdgcn_mfma_f32_16x16x32_bf16(pa[kk], bv, acc[dt], 0,0,0);
      }
    }

    if (pre){
      WRITE(cur^1);
      __syncthreads();
    }
    cur ^= 1;
  }

  #pragma unroll
  for (int dt=0;dt<8;dt++){
    #pragma unroll
    for (int r=0;r<4;r++){
      int qi = qlo + w*16 + lg*4 + r;
      out[(size_t)(b*QLEN+qi)*(NH*HD) + h*HD + dt*16 + l16] = acc[dt][r] / lrun[r];
    }
  }
}

extern "C" void kernel_launch(void* const* d_in, const int* in_sizes, int n_in,
                              void* d_out, int out_size, void* d_ws, size_t ws_size,
                              hipStream_t stream) {
  const float* q = (const float*)d_in[0];
  const float* k = (const float*)d_in[1];
  const float* v = (const float*)d_in[2];
  float*       cache = (float*)d_in[3];
  const int*   slot_mapping = (const int*)d_in[4];
  const int*   block_tables = (const int*)d_in[5];
  float* out = (float*)d_out;

  const size_t need = (size_t)2 * NUM_B * NKVH * NTILES * TILE_BYTES;  // 32 MB
  if (ws_size >= need){
    unsigned short* KT = (unsigned short*)d_ws;
    unsigned short* VT = KT + (need/2)/2;    // second half of ws, in shorts
    repack<<<NUM_B*NKVH*NTILES, 256, 0, stream>>>(k, v, cache, block_tables, KT, VT);
    attn_bf16<<<NUM_B*NKVH*16, 256, 0, stream>>>(q, KT, VT, out);
  } else {
    scatter_kv<<<NUM_B*QLEN, 256, 0, stream>>>(k, v, cache, slot_mapping);
    paged_attn<<<NUM_B*NKVH*8, 512, 0, stream>>>(q, cache, block_tables, out);
  }
}